// Round 6
// baseline (218.409 us; speedup 1.0000x reference)
//
#include <hip/hip_runtime.h>
#include <stdint.h>

// LIF forward scan: u = 0.5*u + x[t] - 0.5*o ; o = (u - 0.5 > 0) ? 1 : 0
// x: [32, 8192, 200] f32, time contiguous. 262144 independent rows.
//
// R6: store-decoupled, depth-3 global_load_lds pipeline.
// Diagnosis R1-R5: vmcnt retires IN ORDER and loads/stores share it; every
// prior structure's load-wait transitively required retiring the previous
// chunk's stores (R4 worst: zero slack, 208us). Also, register-buffered
// pipelines collapse under the register allocator (R2/R5: VGPR=40-52).
// Fix:
//  - global_load_lds staging (no VGPR data targets -> cannot collapse).
//  - 4 wave-private 2KB LDS buffers, depth-3 prefetch: chunk i computes
//    while i+1,i+2,i+3 loads are in flight (6KB/wave, ~96KB/CU >> ~10KB
//    Little's-law need for 6.3TB/s).
//  - Counted waits: N = (#ops issued after the target gll batch) so a wait
//    only ever requires LOAD retirement; stores get >=3 iterations of slack
//    before in-order retirement can touch them.
//  - 200 = 25 chunks x 8 steps, no tail. h-major LDS layout: lanes 0..7 of
//    a ds_read_b128 span all 32 banks -> minimal aliasing (conflict-free).
//  - No __syncthreads anywhere (wave-private buffers only).
// Arithmetic uses __f*_rn to forbid FMA contraction (bit-exact vs numpy
// order; a spike flip near threshold is absmax=1.0).

#define STEPS 200
#define RPB 256

typedef __attribute__((address_space(3))) uint32_t lds_u32;
typedef __attribute__((address_space(1))) const uint32_t glb_u32;

// literal-N counted wait; sched_barrier keeps following mem ops below it
#define WAITCNT(n) do { asm volatile("s_waitcnt vmcnt(" #n ")" ::: "memory"); \
                        __builtin_amdgcn_sched_barrier(0); } while (0)

__device__ __forceinline__ void lif_step(float& u, float& o, float xi) {
    float a = __fmul_rn(0.5f, u);
    float s = __fadd_rn(a, xi);
    float d = __fmul_rn(0.5f, o);
    u = __fsub_rn(s, d);
    o = (u > 0.5f) ? 1.0f : 0.0f;
}

// stage one 8-step chunk (2KB) for this wave's 64 rows: 2 gll insts.
// gll writes LDS at (uniform base + lane*16); source is per-lane.
// buf slot (16B units): h*64 + lane  <->  row=lane, floats t0+4h .. t0+4h+3
__device__ __forceinline__ void stage(const float* __restrict__ xr, float4* buf, int t0) {
    __builtin_amdgcn_global_load_lds((const glb_u32*)(xr + t0),     (lds_u32*)(buf),      16, 0, 0);
    __builtin_amdgcn_global_load_lds((const glb_u32*)(xr + t0 + 4), (lds_u32*)(buf + 64), 16, 0, 0);
}

// compute 8 steps from buf (row = lane), 2 direct float4 spike stores
__device__ __forceinline__ void comp8(const float4* buf, float* __restrict__ orow,
                                      int lane, int t0, float& u, float& o) {
    float4 a = buf[lane];
    float4 b = buf[64 + lane];
    lif_step(u, o, a.x); float o0 = o;
    lif_step(u, o, a.y); float o1 = o;
    lif_step(u, o, a.z); float o2 = o;
    lif_step(u, o, a.w); float o3 = o;
    *reinterpret_cast<float4*>(orow + t0) = make_float4(o0, o1, o2, o3);
    lif_step(u, o, b.x); o0 = o;
    lif_step(u, o, b.y); o1 = o;
    lif_step(u, o, b.z); o2 = o;
    lif_step(u, o, b.w); o3 = o;
    *reinterpret_cast<float4*>(orow + t0 + 4) = make_float4(o0, o1, o2, o3);
}

__global__ __launch_bounds__(RPB, 4) void lif_kernel(
    const float* __restrict__ x, float* __restrict__ out)
{
    __shared__ float4 tile[2048];              // 4 waves x 4 bufs x 128 slots = 32 KB
    const int tid  = threadIdx.x;
    const int w    = tid >> 6;
    const int lane = tid & 63;
    const long long row = (long long)blockIdx.x * RPB + tid;  // one row per lane
    const float* xr = x + row * STEPS;
    float* orow = out + row * STEPS;
    float4* bufs = &tile[w * 512];             // wave-private: 4 x 128 slots

    float u = 0.0f, o = 0.0f;

    // prologue: fill pipeline 3 deep
    stage(xr, bufs + 0 * 128, 0);
    stage(xr, bufs + 1 * 128, 8);
    stage(xr, bufs + 2 * 128, 16);

    // peeled starts (N = exact count of ops newer than target gll pair)
    stage(xr, bufs + 3 * 128, 24);  WAITCNT(6);  comp8(bufs + 0 * 128, orow, lane, 0,  u, o);
    stage(xr, bufs + 0 * 128, 32);  WAITCNT(8);  comp8(bufs + 1 * 128, orow, lane, 8,  u, o);
    stage(xr, bufs + 1 * 128, 40);  WAITCNT(10); comp8(bufs + 2 * 128, orow, lane, 16, u, o);

    // steady state: ch = 3..21, stage ch+3, wait = 3 gll pairs + 3 store pairs
#pragma unroll
    for (int ch = 3; ch < 22; ++ch) {
        stage(xr, bufs + ((ch + 3) & 3) * 128, (ch + 3) * 8);
        WAITCNT(12);
        comp8(bufs + (ch & 3) * 128, orow, lane, ch * 8, u, o);
    }

    // epilogue: drain (no new stages; N shrinks by one gll pair each step)
    WAITCNT(10); comp8(bufs + 2 * 128, orow, lane, 176, u, o);   // ch=22
    WAITCNT(8);  comp8(bufs + 3 * 128, orow, lane, 184, u, o);   // ch=23
    WAITCNT(6);  comp8(bufs + 0 * 128, orow, lane, 192, u, o);   // ch=24
}

extern "C" void kernel_launch(void* const* d_in, const int* in_sizes, int n_in,
                              void* d_out, int out_size, void* d_ws, size_t ws_size,
                              hipStream_t stream)
{
    const float* x = (const float*)d_in[0];
    float* out = (float*)d_out;
    int nrows = in_sizes[0] / STEPS;   // 262144
    int grid = nrows / RPB;            // 1024 blocks = 4 per CU, exact
    lif_kernel<<<grid, RPB, 0, stream>>>(x, out);
}

// Round 7
// 116.993 us; speedup vs baseline: 1.8669x; 1.8669x over previous
//
#include <hip/hip_runtime.h>
#include <stdint.h>

// LIF forward scan: u = 0.5*u + x[t] - 0.5*o ; o = (u - 0.5 > 0) ? 1 : 0
// x: [32, 8192, 200] f32, time contiguous. 262144 independent rows.
//
// R7: full-row batches -> perfectly contiguous memory transactions.
// LCM(800B row, 1KB wave-load) = 25KB = 32 COMPLETE rows:
//  - stage batch = 25 contiguous 1KB global_load_lds (8 fully-used aligned
//    lines per instr, copy-like; kills the strided-segment transaction tax
//    of R1-R6 where every instr touched 16-64 scattered lines).
//  - the whole 200-step scan runs in-LDS per batch (no inter-chunk carry);
//    lanes 0-31 each own one row; spikes overwrite x in place.
//  - store batch = 25 contiguous 1KB global_store_dwordx4 (WRITE ideal;
//    R5/R6's scattered stores showed 270-315MB vs 212 ideal).
//  - rotation swizzle slot(r,k) = r*50 + (k+r)%50 folded into the per-lane
//    gll SOURCE address (LDS dest stays linear); compute reads then spread
//    across banks (~min aliasing for 32-lane b128).
//  - 1 wave/block, 128 rows = 4 batches, A/B 25KB buffers; 3 blocks/CU
//    resident -> up to 75KB/CU loads in flight. Counted vmcnt waits never
//    require a store younger than ~1 full iteration (store-decoupled).
// Arithmetic uses __f*_rn to forbid FMA contraction (bit-exact vs numpy
// order; a spike flip near threshold is absmax=1.0).

#define STEPS 200
#define SEGS 50            // 16B segments per row
#define RPBATCH 32         // rows per batch (the LCM unit)
#define SLOTS 1600         // float4 slots per buffer = 32*50
#define BATCH_FLOATS 6400  // 32 rows * 200 steps
#define ROWS_PER_BLOCK 128 // 4 batches

typedef __attribute__((address_space(3))) uint32_t lds_u32;
typedef __attribute__((address_space(1))) const uint32_t glb_u32;

#define WAITV(n) do { asm volatile("s_waitcnt vmcnt(" #n ")" ::: "memory"); \
                      __builtin_amdgcn_sched_barrier(0); } while (0)
#define WAITL()  do { asm volatile("s_waitcnt lgkmcnt(0)" ::: "memory"); \
                      __builtin_amdgcn_sched_barrier(0); } while (0)

__device__ __forceinline__ void lif_step(float& u, float& o, float xi) {
    float a = __fmul_rn(0.5f, u);
    float s = __fadd_rn(a, xi);
    float d = __fmul_rn(0.5f, o);
    u = __fsub_rn(s, d);
    o = (u > 0.5f) ? 1.0f : 0.0f;
}

// Stage one 32-row batch: 25 contiguous 1KB gll. LDS slot s'=i*64+lane is
// linear (HW: uniform base + lane*16); source is pre-swizzled: slot s' holds
// row r=s'/50, rotated col j=s'%50 -> actual segment k=(j-r) mod 50.
__device__ __forceinline__ void stage(const float* __restrict__ gb,
                                      float4* buf, int lane) {
#pragma unroll
    for (int i = 0; i < 25; ++i) {
        int s = i * 64 + lane;
        int r = s / 50, j = s % 50;          // compiler: magic-mul
        int k = j - r; k += (k >> 31) & SEGS;
        __builtin_amdgcn_global_load_lds((const glb_u32*)(gb + r * STEPS + k * 4),
                                         (lds_u32*)(buf + i * 64), 16, 0, 0);
    }
}

// Full 200-step scan; lane r owns row r (r<32). Spikes overwrite x in place.
__device__ __forceinline__ void comp(float4* buf, int lane) {
    if (lane < RPBATCH) {
        float u = 0.0f, o = 0.0f;
        float4* rowb = buf + lane * SEGS;
        int j = lane;                        // (k + r) % 50 at k=0
#pragma unroll 2
        for (int k = 0; k < SEGS; ++k) {
            float4 v = rowb[j];
            lif_step(u, o, v.x); float o0 = o;
            lif_step(u, o, v.y); float o1 = o;
            lif_step(u, o, v.z); float o2 = o;
            lif_step(u, o, v.w); float o3 = o;
            rowb[j] = make_float4(o0, o1, o2, o3);
            ++j; if (j == SEGS) j = 0;
        }
    }
}

// Store one batch: 25 contiguous 1KB stores. Global segment s=i*64+lane ->
// row r=s/50, seg k=s%50, read LDS slot r*50+(k+r)%50.
__device__ __forceinline__ void store_b(float* __restrict__ gb,
                                        const float4* buf, int lane) {
#pragma unroll
    for (int i = 0; i < 25; ++i) {
        int s = i * 64 + lane;
        int r = s / 50, k = s % 50;
        int j = k + r; if (j >= SEGS) j -= SEGS;
        float4 v = buf[r * SEGS + j];
        *reinterpret_cast<float4*>(gb + s * 4) = v;
    }
}

__global__ __launch_bounds__(64) void lif_kernel(const float* __restrict__ x,
                                                 float* __restrict__ out)
{
    __shared__ float4 tile[2 * SLOTS];       // 50 KB -> 3 blocks/CU
    const int lane = threadIdx.x;
    const long long row0 = (long long)blockIdx.x * ROWS_PER_BLOCK;
    const float* xb = x + row0 * STEPS;
    float* ob = out + row0 * STEPS;
    float4* A = tile;
    float4* B = tile + SLOTS;

    stage(xb + 0 * BATCH_FLOATS, A, lane);   // 25 out
    stage(xb + 1 * BATCH_FLOATS, B, lane);   // 50 out

    WAITV(25);                               // stage0 done; stage1 in flight
    comp(A, lane);
    store_b(ob + 0 * BATCH_FLOATS, A, lane);
    WAITL();                                 // store's ds_reads done before overwrite
    stage(xb + 2 * BATCH_FLOATS, A, lane);

    WAITV(50);                               // stage1 done; store0+stage2 in flight
    comp(B, lane);
    store_b(ob + 1 * BATCH_FLOATS, B, lane);
    WAITL();
    stage(xb + 3 * BATCH_FLOATS, B, lane);

    WAITV(50);                               // stage2 done (store0 had a full iter)
    comp(A, lane);
    store_b(ob + 2 * BATCH_FLOATS, A, lane);

    WAITV(25);                               // stage3 done; store2 in flight
    comp(B, lane);
    store_b(ob + 3 * BATCH_FLOATS, B, lane);
}

extern "C" void kernel_launch(void* const* d_in, const int* in_sizes, int n_in,
                              void* d_out, int out_size, void* d_ws, size_t ws_size,
                              hipStream_t stream)
{
    const float* x = (const float*)d_in[0];
    float* out = (float*)d_out;
    int nrows = in_sizes[0] / STEPS;           // 262144
    int grid = nrows / ROWS_PER_BLOCK;         // 2048 blocks x 1 wave
    lif_kernel<<<grid, 64, 0, stream>>>(x, out);
}